// Round 7
// baseline (149.449 us; speedup 1.0000x reference)
//
#include <hip/hip_runtime.h>

#define D_MODEL 1024
#define HDIM    64
#define BATCH   8
#define SEQ     2048
#define BT      (BATCH*SEQ)
#define NCAT    192

typedef __attribute__((ext_vector_type(8))) short s8v;
typedef __attribute__((ext_vector_type(4))) float f4;
typedef __attribute__((ext_vector_type(4))) unsigned short u16x4;

__device__ __forceinline__ unsigned short f2bf(float f){
    unsigned u = __builtin_bit_cast(unsigned, f);
    u += 0x7fffu + ((u >> 16) & 1u);
    return (unsigned short)(u >> 16);
}
__device__ __forceinline__ float bf2f(unsigned short h){
    unsigned u = ((unsigned)h) << 16;
    return __builtin_bit_cast(float, u);
}
__device__ __forceinline__ f4 MFMA(s8v a, s8v b, f4 c){
    return __builtin_amdgcn_mfma_f32_16x16x32_bf16(a, b, c, 0, 0, 0);
}

// ---- kernel 1: W -> Wt[192][1024] bf16 hi/lo (transposed, concatenated q|k|v) ----
__global__ void prep_w_kernel(const float* __restrict__ wq, const float* __restrict__ wk,
                              const float* __restrict__ wv,
                              short* __restrict__ wtH, short* __restrict__ wtL){
    int ncat = blockIdx.x;
    const float* w = (ncat < 64) ? wq : ((ncat < 128) ? wk : wv);
    int n = ncat & 63;
    for (int k = threadIdx.x; k < D_MODEL; k += blockDim.x){
        float f = w[k*HDIM + n];
        unsigned short h = f2bf(f);
        wtH[ncat*D_MODEL + k] = (short)h;
        wtL[ncat*D_MODEL + k] = (short)f2bf(f - bf2f(h));
    }
}

// ---- kernel 2: fused QKV projection, bf16 hi/lo MFMA (fp32-accurate) ----
// Outputs: qh/ql, kh/kl row-major [BT][64] bf16; vt transposed [B][64][T] bf16.
__global__ __launch_bounds__(512) void proj_kernel(
        const float* __restrict__ x,
        const short* __restrict__ wtH, const short* __restrict__ wtL,
        short* __restrict__ qh, short* __restrict__ ql,
        short* __restrict__ kh, short* __restrict__ kl,
        short* __restrict__ vt){
    // stride 40 shorts = 80B: 16B-aligned rows, conflict-light b128 frag reads
    __shared__ short xsH[64][40], xsL[64][40];
    __shared__ short wsH[NCAT][40], wsL[NCAT][40];
    int tid = threadIdx.x;
    int m0 = blockIdx.x * 64;
    int wid = tid >> 6, lane = tid & 63, g = lane >> 4, ln = lane & 15;
    int wm = wid & 3, wn = wid >> 2;   // wave tile: rows wm*16..+15, cols wn*96..+95
    f4 acc[6];
#pragma unroll
    for (int i = 0; i < 6; i++) acc[i] = (f4){0.f,0.f,0.f,0.f};

    for (int k0 = 0; k0 < D_MODEL; k0 += 32){
        __syncthreads();
        {   // stage x tile 64x32: fp32 -> bf16 hi/lo
            int row = tid >> 3, kc = (tid & 7) << 2;
            float4 xv = *(const float4*)(x + (size_t)(m0 + row)*D_MODEL + k0 + kc);
            u16x4 hv, lv;
            float f0 = xv.x, f1 = xv.y, f2 = xv.z, f3 = xv.w;
            unsigned short h0 = f2bf(f0), h1 = f2bf(f1), h2 = f2bf(f2), h3 = f2bf(f3);
            hv[0]=h0; hv[1]=h1; hv[2]=h2; hv[3]=h3;
            lv[0]=f2bf(f0-bf2f(h0)); lv[1]=f2bf(f1-bf2f(h1));
            lv[2]=f2bf(f2-bf2f(h2)); lv[3]=f2bf(f3-bf2f(h3));
            *(u16x4*)&xsH[row][kc] = hv;
            *(u16x4*)&xsL[row][kc] = lv;
        }
        // stage Wt tile 192x32 (hi and lo), 16B chunks
        for (int i = tid; i < NCAT*4; i += 512){
            int row = i >> 2, c = (i & 3) << 3;
            *(s8v*)&wsH[row][c] = *(const s8v*)(wtH + row*D_MODEL + k0 + c);
            *(s8v*)&wsL[row][c] = *(const s8v*)(wtL + row*D_MODEL + k0 + c);
        }
        __syncthreads();
        s8v aH = *(const s8v*)&xsH[wm*16 + ln][g*8];
        s8v aL = *(const s8v*)&xsL[wm*16 + ln][g*8];
#pragma unroll
        for (int nb = 0; nb < 6; nb++){
            int n = wn*96 + nb*16 + ln;
            s8v bH = *(const s8v*)&wsH[n][g*8];
            s8v bL = *(const s8v*)&wsL[n][g*8];
            acc[nb] = MFMA(aH, bH, acc[nb]);
            acc[nb] = MFMA(aL, bH, acc[nb]);   // x_lo * w_hi
            acc[nb] = MFMA(aH, bL, acc[nb]);   // x_hi * w_lo
        }
    }
#pragma unroll
    for (int nb = 0; nb < 6; nb++){
        int ncat = wn*96 + nb*16 + ln;
        int mat = ncat >> 6, h = ncat & 63;
#pragma unroll
        for (int r = 0; r < 4; r++){
            size_t trow = (size_t)m0 + wm*16 + g*4 + r;
            float v = acc[nb][r];
            unsigned short hh = f2bf(v);
            if (mat == 0){
                qh[trow*HDIM + h] = (short)hh;
                ql[trow*HDIM + h] = (short)f2bf(v - bf2f(hh));
            } else if (mat == 1){
                kh[trow*HDIM + h] = (short)hh;
                kl[trow*HDIM + h] = (short)f2bf(v - bf2f(hh));
            } else {
                size_t bb = trow >> 11, t = trow & 2047;
                vt[((bb*HDIM + h) << 11) + t] = (short)hh;
            }
        }
    }
}

// ---- kernel 3: causal flash attention, in-block KV-split (flash-decode style) ----
// One block = one 16-row Q strip. 4 waves each own a strided subset of KV tiles
// with private (o, m, l); partials combined in LDS at block end (exact algebra).
__global__ __launch_bounds__(256) void attn_kernel(
        const short* __restrict__ qh, const short* __restrict__ ql,
        const short* __restrict__ kh, const short* __restrict__ kl,
        const short* __restrict__ vt, float* __restrict__ out){
    __shared__ unsigned short plds[4][16][48];   // wave-private P tiles, 96B row stride
    __shared__ float olds[4][16][65];            // partial O, stride 65 = conflict-free
    __shared__ float mlds[4][16], llds[4][16];
    const float SC = 0.125f * 1.44269504088896340736f;  // 1/sqrt(64) * log2(e)
    int tid = threadIdx.x;
    int w = tid >> 6, lane = tid & 63, g = lane >> 4, ln = lane & 15;
    int b = blockIdx.y;
    int qi = gridDim.x - 1 - blockIdx.x;   // longest strips dispatched first
    int tq = qi * 16;

    // all 4 waves load the same 16-row Q strip (hi/lo)
    size_t qoff = ((size_t)b*SEQ + tq + ln) * HDIM + g*8;
    s8v q0h = *(const s8v*)(qh + qoff);
    s8v q1h = *(const s8v*)(qh + qoff + 32);
    s8v q0l = *(const s8v*)(ql + qoff);
    s8v q1l = *(const s8v*)(ql + qoff + 32);

    f4 o0 = {0.f,0.f,0.f,0.f}, o1 = o0, o2 = o0, o3 = o0;
    float m[4], lsum[4];
#pragma unroll
    for (int r = 0; r < 4; r++){ m[r] = -__builtin_inff(); lsum[r] = 0.f; }

    int ntiles = (tq + 47) >> 5;   // ceil((tq+16)/32)
    for (int ti = w; ti < ntiles; ti += 4){   // KV-split: wave w takes tiles w, w+4, ...
        int s0 = ti << 5;
        size_t koff = ((size_t)b*SEQ + s0 + ln) * HDIM + g*8;
        s8v ka0h = *(const s8v*)(kh + koff);
        s8v ka1h = *(const s8v*)(kh + koff + 32);
        s8v kb0h = *(const s8v*)(kh + koff + 16*HDIM);
        s8v kb1h = *(const s8v*)(kh + koff + 16*HDIM + 32);
        s8v ka0l = *(const s8v*)(kl + koff);
        s8v ka1l = *(const s8v*)(kl + koff + 32);
        s8v kb0l = *(const s8v*)(kl + koff + 16*HDIM);
        s8v kb1l = *(const s8v*)(kl + koff + 16*HDIM + 32);

        f4 sa = {0.f,0.f,0.f,0.f}, sb = sa;
        sa = MFMA(q0h, ka0h, sa); sa = MFMA(q1h, ka1h, sa);
        sa = MFMA(q0l, ka0h, sa); sa = MFMA(q1l, ka1h, sa);
        sa = MFMA(q0h, ka0l, sa); sa = MFMA(q1h, ka1l, sa);
        sb = MFMA(q0h, kb0h, sb); sb = MFMA(q1h, kb1h, sb);
        sb = MFMA(q0l, kb0h, sb); sb = MFMA(q1l, kb1h, sb);
        sb = MFMA(q0h, kb0l, sb); sb = MFMA(q1h, kb1l, sb);

        float z0[4], z1[4];
#pragma unroll
        for (int r = 0; r < 4; r++){ z0[r] = sa[r]*SC; z1[r] = sb[r]*SC; }
        if (s0 + 31 > tq){   // causal mask (only near-diagonal tiles)
#pragma unroll
            for (int r = 0; r < 4; r++){
                int t = tq + g*4 + r;
                if (s0 + ln      > t) z0[r] = -__builtin_inff();
                if (s0 + 16 + ln > t) z1[r] = -__builtin_inff();
            }
        }
        float al[4];
#pragma unroll
        for (int r = 0; r < 4; r++){
            float v = fmaxf(z0[r], z1[r]);
            v = fmaxf(v, __shfl_xor(v, 1));
            v = fmaxf(v, __shfl_xor(v, 2));
            v = fmaxf(v, __shfl_xor(v, 4));
            v = fmaxf(v, __shfl_xor(v, 8));
            float mn = fmaxf(m[r], v);
            al[r] = __builtin_amdgcn_exp2f(m[r] - mn);
            float p0 = __builtin_amdgcn_exp2f(z0[r] - mn);
            float p1 = __builtin_amdgcn_exp2f(z1[r] - mn);
            float s = p0 + p1;
            s += __shfl_xor(s, 1);
            s += __shfl_xor(s, 2);
            s += __shfl_xor(s, 4);
            s += __shfl_xor(s, 8);
            lsum[r] = lsum[r] * al[r] + s;
            m[r] = mn;
            plds[w][g*4 + r][ln]      = f2bf(p0);
            plds[w][g*4 + r][ln + 16] = f2bf(p1);
        }
#pragma unroll
        for (int r = 0; r < 4; r++){
            o0[r] *= al[r]; o1[r] *= al[r]; o2[r] *= al[r]; o3[r] *= al[r];
        }
        asm volatile("s_waitcnt lgkmcnt(0)" ::: "memory");  // cross-lane P write->read
        __builtin_amdgcn_sched_barrier(0);
        s8v pa = *(const s8v*)&plds[w][ln][g*8];
        size_t voff = ((size_t)b*HDIM + ln) * SEQ + s0 + g*8;
        s8v v0 = *(const s8v*)(vt + voff);
        s8v v1 = *(const s8v*)(vt + voff + 16*SEQ);
        s8v v2 = *(const s8v*)(vt + voff + 32*SEQ);
        s8v v3 = *(const s8v*)(vt + voff + 48*SEQ);
        o0 = MFMA(pa, v0, o0);
        o1 = MFMA(pa, v1, o1);
        o2 = MFMA(pa, v2, o2);
        o3 = MFMA(pa, v3, o3);
    }

    // ---- write per-wave partials to LDS ----
#pragma unroll
    for (int r = 0; r < 4; r++){
        int row = g*4 + r;
        olds[w][row][ln]      = o0[r];
        olds[w][row][ln + 16] = o1[r];
        olds[w][row][ln + 32] = o2[r];
        olds[w][row][ln + 48] = o3[r];
        if (ln == 0){ mlds[w][row] = m[r]; llds[w][row] = lsum[r]; }
    }
    __syncthreads();

    // ---- combine 4 partials (exact online-softmax merge), coalesced store ----
    {
        int row = tid >> 4;          // 0..15
        int hb  = tid & 15;          // 0..15
        float m0 = mlds[0][row], m1 = mlds[1][row], m2 = mlds[2][row], m3 = mlds[3][row];
        float M = fmaxf(fmaxf(m0, m1), fmaxf(m2, m3));   // finite: wave 0 always has tile 0
        float w0 = __builtin_amdgcn_exp2f(m0 - M);
        float w1 = __builtin_amdgcn_exp2f(m1 - M);
        float w2 = __builtin_amdgcn_exp2f(m2 - M);
        float w3 = __builtin_amdgcn_exp2f(m3 - M);
        float L = llds[0][row]*w0 + llds[1][row]*w1 + llds[2][row]*w2 + llds[3][row]*w3;
        float inv = 1.0f / L;
        size_t obase = ((size_t)b*SEQ + tq + row) * HDIM + hb;
#pragma unroll
        for (int j = 0; j < 4; j++){
            int h = hb + 16*j;
            float acc = olds[0][row][h]*w0 + olds[1][row][h]*w1
                      + olds[2][row][h]*w2 + olds[3][row][h]*w3;
            out[obase + 16*j] = acc * inv;
        }
    }
}

extern "C" void kernel_launch(void* const* d_in, const int* in_sizes, int n_in,
                              void* d_out, int out_size, void* d_ws, size_t ws_size,
                              hipStream_t stream) {
    (void)in_sizes; (void)n_in; (void)out_size; (void)ws_size;
    const float* x  = (const float*)d_in[0];
    const float* wq = (const float*)d_in[1];
    const float* wk = (const float*)d_in[2];
    const float* wv = (const float*)d_in[3];
    float* out = (float*)d_out;

    short* ws  = (short*)d_ws;               // ~11.3 MB total workspace
    short* wtH = ws;
    short* wtL = wtH + (size_t)NCAT*D_MODEL;
    short* qh  = wtL + (size_t)NCAT*D_MODEL;
    short* ql  = qh + (size_t)BT*HDIM;
    short* kh  = ql + (size_t)BT*HDIM;
    short* kl  = kh + (size_t)BT*HDIM;
    short* vt  = kl + (size_t)BT*HDIM;

    prep_w_kernel<<<NCAT, 256, 0, stream>>>(wq, wk, wv, wtH, wtL);
    proj_kernel<<<BT/64, 512, 0, stream>>>(x, wtH, wtL, qh, ql, kh, kl, vt);
    attn_kernel<<<dim3(SEQ/16, BATCH), 256, 0, stream>>>(qh, ql, kh, kl, vt, out);
}

// Round 8
// 110.213 us; speedup vs baseline: 1.3560x; 1.3560x over previous
//
#include <hip/hip_runtime.h>

#define D_MODEL 1024
#define HDIM    64
#define BATCH   8
#define SEQ     2048
#define BT      (BATCH*SEQ)
#define NCAT    192

typedef __attribute__((ext_vector_type(8))) short s8v;
typedef __attribute__((ext_vector_type(4))) float f4;
typedef __attribute__((ext_vector_type(4))) unsigned short u16x4;

__device__ __forceinline__ unsigned short f2bf(float f){
    unsigned u = __builtin_bit_cast(unsigned, f);
    u += 0x7fffu + ((u >> 16) & 1u);
    return (unsigned short)(u >> 16);
}
__device__ __forceinline__ float bf2f(unsigned short h){
    unsigned u = ((unsigned)h) << 16;
    return __builtin_bit_cast(float, u);
}
__device__ __forceinline__ f4 MFMA(s8v a, s8v b, f4 c){
    return __builtin_amdgcn_mfma_f32_16x16x32_bf16(a, b, c, 0, 0, 0);
}

// ---- kernel 1: W -> Wt[192][1024] bf16 hi/lo (transposed, concatenated q|k|v) ----
__global__ void prep_w_kernel(const float* __restrict__ wq, const float* __restrict__ wk,
                              const float* __restrict__ wv,
                              short* __restrict__ wtH, short* __restrict__ wtL){
    int ncat = blockIdx.x;
    const float* w = (ncat < 64) ? wq : ((ncat < 128) ? wk : wv);
    int n = ncat & 63;
    for (int k = threadIdx.x; k < D_MODEL; k += blockDim.x){
        float f = w[k*HDIM + n];
        unsigned short h = f2bf(f);
        wtH[ncat*D_MODEL + k] = (short)h;
        wtL[ncat*D_MODEL + k] = (short)f2bf(f - bf2f(h));
    }
}

// ---- kernel 2: fused QKV projection, bf16 hi/lo MFMA (fp32-accurate) ----
// Outputs: qh/ql, kh/kl row-major [BT][64] bf16; vt transposed [B][64][T] bf16.
__global__ __launch_bounds__(512) void proj_kernel(
        const float* __restrict__ x,
        const short* __restrict__ wtH, const short* __restrict__ wtL,
        short* __restrict__ qh, short* __restrict__ ql,
        short* __restrict__ kh, short* __restrict__ kl,
        short* __restrict__ vt){
    // stride 40 shorts = 80B: 16B-aligned rows, conflict-light b128 frag reads
    __shared__ short xsH[64][40], xsL[64][40];
    __shared__ short wsH[NCAT][40], wsL[NCAT][40];
    int tid = threadIdx.x;
    int m0 = blockIdx.x * 64;
    int wid = tid >> 6, lane = tid & 63, g = lane >> 4, ln = lane & 15;
    int wm = wid & 3, wn = wid >> 2;   // wave tile: rows wm*16..+15, cols wn*96..+95
    f4 acc[6];
#pragma unroll
    for (int i = 0; i < 6; i++) acc[i] = (f4){0.f,0.f,0.f,0.f};

    for (int k0 = 0; k0 < D_MODEL; k0 += 32){
        __syncthreads();
        {   // stage x tile 64x32: fp32 -> bf16 hi/lo
            int row = tid >> 3, kc = (tid & 7) << 2;
            float4 xv = *(const float4*)(x + (size_t)(m0 + row)*D_MODEL + k0 + kc);
            u16x4 hv, lv;
            float f0 = xv.x, f1 = xv.y, f2 = xv.z, f3 = xv.w;
            unsigned short h0 = f2bf(f0), h1 = f2bf(f1), h2 = f2bf(f2), h3 = f2bf(f3);
            hv[0]=h0; hv[1]=h1; hv[2]=h2; hv[3]=h3;
            lv[0]=f2bf(f0-bf2f(h0)); lv[1]=f2bf(f1-bf2f(h1));
            lv[2]=f2bf(f2-bf2f(h2)); lv[3]=f2bf(f3-bf2f(h3));
            *(u16x4*)&xsH[row][kc] = hv;
            *(u16x4*)&xsL[row][kc] = lv;
        }
        // stage Wt tile 192x32 (hi and lo), 16B chunks
        for (int i = tid; i < NCAT*4; i += 512){
            int row = i >> 2, c = (i & 3) << 3;
            *(s8v*)&wsH[row][c] = *(const s8v*)(wtH + row*D_MODEL + k0 + c);
            *(s8v*)&wsL[row][c] = *(const s8v*)(wtL + row*D_MODEL + k0 + c);
        }
        __syncthreads();
        s8v aH = *(const s8v*)&xsH[wm*16 + ln][g*8];
        s8v aL = *(const s8v*)&xsL[wm*16 + ln][g*8];
#pragma unroll
        for (int nb = 0; nb < 6; nb++){
            int n = wn*96 + nb*16 + ln;
            s8v bH = *(const s8v*)&wsH[n][g*8];
            s8v bL = *(const s8v*)&wsL[n][g*8];
            acc[nb] = MFMA(aH, bH, acc[nb]);
            acc[nb] = MFMA(aL, bH, acc[nb]);   // x_lo * w_hi
            acc[nb] = MFMA(aH, bL, acc[nb]);   // x_hi * w_lo
        }
    }
#pragma unroll
    for (int nb = 0; nb < 6; nb++){
        int ncat = wn*96 + nb*16 + ln;
        int mat = ncat >> 6, h = ncat & 63;
#pragma unroll
        for (int r = 0; r < 4; r++){
            size_t trow = (size_t)m0 + wm*16 + g*4 + r;
            float v = acc[nb][r];
            unsigned short hh = f2bf(v);
            if (mat == 0){
                qh[trow*HDIM + h] = (short)hh;
                ql[trow*HDIM + h] = (short)f2bf(v - bf2f(hh));
            } else if (mat == 1){
                kh[trow*HDIM + h] = (short)hh;
                kl[trow*HDIM + h] = (short)f2bf(v - bf2f(hh));
            } else {
                size_t bb = trow >> 11, t = trow & 2047;
                vt[((bb*HDIM + h) << 11) + t] = (short)hh;
            }
        }
    }
}

// ---- kernel 3: causal flash attention, in-block KV-split, KVBLK=64 ----
// One block = one 16-row Q strip; wave w owns KV tiles w, w+4, ... (64 keys each)
// with private (o, m, l); partials merged in LDS at block end (exact algebra).
// qi swizzle pairs strip x with 127-x on the same CU -> constant per-CU work.
__global__ __launch_bounds__(256, 4) void attn_kernel(
        const short* __restrict__ qh, const short* __restrict__ ql,
        const short* __restrict__ kh, const short* __restrict__ kl,
        const short* __restrict__ vt, float* __restrict__ out){
    __shared__ unsigned short plds[4][16][112];  // wave-private P tiles (stride 224B: 24-word bank pattern)
    __shared__ float olds[4][16][65];            // partial O, stride 65 = conflict-free
    __shared__ float mlds[4][16], llds[4][16];
    const float SC = 0.125f * 1.44269504088896340736f;  // 1/sqrt(64) * log2(e)
    int tid = threadIdx.x;
    int w = tid >> 6, lane = tid & 63, g = lane >> 4, ln = lane & 15;
    int b = blockIdx.y;
    // balance swizzle: CU gets y parity-spaced blocks -> qi alternates x / 127-x
    int qi = ((blockIdx.y >> 1) & 1) ? (int)(gridDim.x - 1 - blockIdx.x) : (int)blockIdx.x;
    int tq = qi * 16;

    // all 4 waves load the same 16-row Q strip (hi/lo)
    size_t qoff = ((size_t)b*SEQ + tq + ln) * HDIM + g*8;
    s8v q0h = *(const s8v*)(qh + qoff);
    s8v q1h = *(const s8v*)(qh + qoff + 32);
    s8v q0l = *(const s8v*)(ql + qoff);
    s8v q1l = *(const s8v*)(ql + qoff + 32);

    f4 o0 = {0.f,0.f,0.f,0.f}, o1 = o0, o2 = o0, o3 = o0;
    float m[4], lsum[4];   // lsum: PER-LANE partial (deferred reduce after loop)
#pragma unroll
    for (int r = 0; r < 4; r++){ m[r] = -__builtin_inff(); lsum[r] = 0.f; }

    int ntiles = (tq + 79) >> 6;   // ceil((tq+16)/64)
    for (int ti = w; ti < ntiles; ti += 4){
        int s0 = ti << 6;
        size_t kbase = ((size_t)b*SEQ + s0 + ln) * HDIM + g*8;
        f4 z0, z1, z2, z3;
#define QK_SUBTILE(ZJ, J) { \
        const short* kph = kh + kbase + (J)*16*HDIM; \
        const short* kpl = kl + kbase + (J)*16*HDIM; \
        s8v k0h = *(const s8v*)(kph); \
        s8v k1h = *(const s8v*)(kph + 32); \
        s8v k0l = *(const s8v*)(kpl); \
        s8v k1l = *(const s8v*)(kpl + 32); \
        f4 s = {0.f,0.f,0.f,0.f}; \
        s = MFMA(q0h, k0h, s); s = MFMA(q1h, k1h, s); \
        s = MFMA(q0l, k0h, s); s = MFMA(q1l, k1h, s); \
        s = MFMA(q0h, k0l, s); s = MFMA(q1h, k1l, s); \
        ZJ[0] = s[0]*SC; ZJ[1] = s[1]*SC; ZJ[2] = s[2]*SC; ZJ[3] = s[3]*SC; }
        QK_SUBTILE(z0, 0)
        QK_SUBTILE(z1, 1)
        QK_SUBTILE(z2, 2)
        QK_SUBTILE(z3, 3)
#undef QK_SUBTILE
        if (s0 + 63 > tq){   // causal mask (near-diagonal tiles only)
#pragma unroll
            for (int r = 0; r < 4; r++){
                int t = tq + g*4 + r;
                if (s0      + ln > t) z0[r] = -__builtin_inff();
                if (s0 + 16 + ln > t) z1[r] = -__builtin_inff();
                if (s0 + 32 + ln > t) z2[r] = -__builtin_inff();
                if (s0 + 48 + ln > t) z3[r] = -__builtin_inff();
            }
        }
        float al[4];
#pragma unroll
        for (int r = 0; r < 4; r++){
            float v = fmaxf(fmaxf(z0[r], z1[r]), fmaxf(z2[r], z3[r]));
            v = fmaxf(v, __shfl_xor(v, 1));
            v = fmaxf(v, __shfl_xor(v, 2));
            v = fmaxf(v, __shfl_xor(v, 4));
            v = fmaxf(v, __shfl_xor(v, 8));
            float mn = fmaxf(m[r], v);
            al[r] = __builtin_amdgcn_exp2f(m[r] - mn);
            float p0 = __builtin_amdgcn_exp2f(z0[r] - mn);
            float p1 = __builtin_amdgcn_exp2f(z1[r] - mn);
            float p2 = __builtin_amdgcn_exp2f(z2[r] - mn);
            float p3 = __builtin_amdgcn_exp2f(z3[r] - mn);
            lsum[r] = lsum[r]*al[r] + ((p0 + p1) + (p2 + p3));  // lane-partial, no shfl
            m[r] = mn;
            int row = g*4 + r;
            plds[w][row][ln]      = f2bf(p0);
            plds[w][row][ln + 16] = f2bf(p1);
            plds[w][row][ln + 32] = f2bf(p2);
            plds[w][row][ln + 48] = f2bf(p3);
        }
#pragma unroll
        for (int r = 0; r < 4; r++){
            o0[r] *= al[r]; o1[r] *= al[r]; o2[r] *= al[r]; o3[r] *= al[r];
        }
        asm volatile("s_waitcnt lgkmcnt(0)" ::: "memory");  // cross-lane P write->read
        __builtin_amdgcn_sched_barrier(0);
        s8v pa0 = *(const s8v*)&plds[w][ln][g*8];
        s8v pa1 = *(const s8v*)&plds[w][ln][32 + g*8];
        size_t voff = ((size_t)b*HDIM + ln) * SEQ + s0 + g*8;
        s8v v00 = *(const s8v*)(vt + voff);
        s8v v01 = *(const s8v*)(vt + voff + 32);
        s8v v10 = *(const s8v*)(vt + voff + 16*SEQ);
        s8v v11 = *(const s8v*)(vt + voff + 16*SEQ + 32);
        s8v v20 = *(const s8v*)(vt + voff + 32*SEQ);
        s8v v21 = *(const s8v*)(vt + voff + 32*SEQ + 32);
        s8v v30 = *(const s8v*)(vt + voff + 48*SEQ);
        s8v v31 = *(const s8v*)(vt + voff + 48*SEQ + 32);
        o0 = MFMA(pa0, v00, o0); o0 = MFMA(pa1, v01, o0);
        o1 = MFMA(pa0, v10, o1); o1 = MFMA(pa1, v11, o1);
        o2 = MFMA(pa0, v20, o2); o2 = MFMA(pa1, v21, o2);
        o3 = MFMA(pa0, v30, o3); o3 = MFMA(pa1, v31, o3);
    }

    // deferred l-sum reduce (once per wave, off the per-tile critical path)
#pragma unroll
    for (int r = 0; r < 4; r++){
        float s = lsum[r];
        s += __shfl_xor(s, 1);
        s += __shfl_xor(s, 2);
        s += __shfl_xor(s, 4);
        s += __shfl_xor(s, 8);
        lsum[r] = s;
    }

    // ---- write per-wave partials to LDS ----
#pragma unroll
    for (int r = 0; r < 4; r++){
        int row = g*4 + r;
        olds[w][row][ln]      = o0[r];
        olds[w][row][ln + 16] = o1[r];
        olds[w][row][ln + 32] = o2[r];
        olds[w][row][ln + 48] = o3[r];
        if (ln == 0){ mlds[w][row] = m[r]; llds[w][row] = lsum[r]; }
    }
    __syncthreads();

    // ---- combine 4 partials (exact online-softmax merge), coalesced store ----
    {
        int row = tid >> 4;          // 0..15
        int hb  = tid & 15;          // 0..15
        float m0 = mlds[0][row], m1 = mlds[1][row], m2 = mlds[2][row], m3 = mlds[3][row];
        float M = fmaxf(fmaxf(m0, m1), fmaxf(m2, m3));   // finite: wave 0 always has tile 0
        float w0 = __builtin_amdgcn_exp2f(m0 - M);
        float w1 = __builtin_amdgcn_exp2f(m1 - M);
        float w2 = __builtin_amdgcn_exp2f(m2 - M);
        float w3 = __builtin_amdgcn_exp2f(m3 - M);
        float L = llds[0][row]*w0 + llds[1][row]*w1 + llds[2][row]*w2 + llds[3][row]*w3;
        float inv = 1.0f / L;
        size_t obase = ((size_t)b*SEQ + tq + row) * HDIM + hb;
#pragma unroll
        for (int j = 0; j < 4; j++){
            int h = hb + 16*j;
            float acc = olds[0][row][h]*w0 + olds[1][row][h]*w1
                      + olds[2][row][h]*w2 + olds[3][row][h]*w3;
            out[obase + 16*j] = acc * inv;
        }
    }
}

extern "C" void kernel_launch(void* const* d_in, const int* in_sizes, int n_in,
                              void* d_out, int out_size, void* d_ws, size_t ws_size,
                              hipStream_t stream) {
    (void)in_sizes; (void)n_in; (void)out_size; (void)ws_size;
    const float* x  = (const float*)d_in[0];
    const float* wq = (const float*)d_in[1];
    const float* wk = (const float*)d_in[2];
    const float* wv = (const float*)d_in[3];
    float* out = (float*)d_out;

    short* ws  = (short*)d_ws;               // ~11.3 MB total workspace
    short* wtH = ws;
    short* wtL = wtH + (size_t)NCAT*D_MODEL;
    short* qh  = wtL + (size_t)NCAT*D_MODEL;
    short* ql  = qh + (size_t)BT*HDIM;
    short* kh  = ql + (size_t)BT*HDIM;
    short* kl  = kh + (size_t)BT*HDIM;
    short* vt  = kl + (size_t)BT*HDIM;

    prep_w_kernel<<<NCAT, 256, 0, stream>>>(wq, wk, wv, wtH, wtL);
    proj_kernel<<<BT/64, 512, 0, stream>>>(x, wtH, wtL, qh, ql, kh, kl, vt);
    attn_kernel<<<dim3(SEQ/16, BATCH), 256, 0, stream>>>(qh, ql, kh, kl, vt, out);
}